// Round 1
// 404.003 us; speedup vs baseline: 1.0089x; 1.0089x over previous
//
#include <hip/hip_runtime.h>
#include <stdint.h>

#define G  128
#define TT 96
#define NB 2
#define NC 4
#define CS (TT * TT * TT)

typedef float f32x4 __attribute__((ext_vector_type(4)));

// Prepass: template [B,C,z,y,x] fp32 -> channels-last float4 [B,z,y,x] (16B/voxel)
// nt loads: template raw is read exactly once here; keep L2 for the packed copy.
__global__ __launch_bounds__(256) void tmpl_repack_kernel(
        const float* __restrict__ tmpl, f32x4* __restrict__ out) {
    const int NV = NB * CS;
    int idx = blockIdx.x * 256 + threadIdx.x;
    if (idx >= NV) return;
    int b = idx / CS;
    int s = idx - b * CS;
    const float* base = tmpl + (size_t)b * NC * CS + s;
    f32x4 p;
    p.x = __builtin_nontemporal_load(base);
    p.y = __builtin_nontemporal_load(base + CS);
    p.z = __builtin_nontemporal_load(base + 2 * CS);
    p.w = __builtin_nontemporal_load(base + 3 * CS);
    out[idx] = p;   // normal store: packed template is the gather working set
}

// One block = tile of 32(d) x 32(w) at fixed (b, h).
// Single LDS buffer [c][j=d][i=w]: stage1 transposes on the LDS-write side;
// stage2 reads def and overwrites the SAME slot with tanh(field) (slot
// ownership is unique per thread -> race-free with the two barriers).
// LDS 25.6KB -> 12.7KB: 6 -> 8 blocks/CU, 24 -> 32 waves/CU.
template <bool PACKED>
__global__ __launch_bounds__(256, 8) void fused_sample_kernel(
        const float* __restrict__ grids,
        const float* __restrict__ deform,
        const float* __restrict__ corr,
        const f32x4* __restrict__ tmpl_cl,    // used when PACKED
        const float* __restrict__ tmpl_raw,   // used when !PACKED
        float* __restrict__ out2,
        float* __restrict__ defp) {
    __shared__ float lds[3][32][33];    // [c][j=d][i=w] (+1 pad)

    int blk = blockIdx.x;
    int wt = blk & 3;
    int dt = (blk >> 2) & 3;
    int h  = (blk >> 4) & 127;
    int b  = blk >> 11;
    int w0 = wt << 5, d0 = dt << 5;
    int tid = threadIdx.x;

    // ---- stage 1: deformation -> lds[c][j][i], 16B vector loads along d,
    //      transposed scatter into LDS (4x ds_write_b32, stride 33 floats)
    for (int idx = tid; idx < 768; idx += 256) {   // 3c * 32i * 8 quads
        int c   = idx >> 8;
        int rem = idx & 255;
        int i   = rem >> 3;
        int j4  = (rem & 7) << 2;
        size_t off = ((((size_t)b * 3 + c) * G + (w0 + i)) * G + h) * G + (d0 + j4);
        f32x4 v = __builtin_nontemporal_load((const f32x4*)(deform + off));
        lds[c][j4 + 0][i] = v.x;
        lds[c][j4 + 1][i] = v.y;
        lds[c][j4 + 2][i] = v.z;
        lds[c][j4 + 3][i] = v.w;
    }
    __syncthreads();

    // ---- stage 2: grids row (96 floats contiguous in (w,c)) -> field in-place;
    //      defp write (exact pass-through of deform)
    for (int idx = tid; idx < 768; idx += 256) {   // 32 rows * 24 float4-chunks
        int j = idx / 24;
        int t = idx - j * 24;
        size_t off = (((((size_t)b * G + (d0 + j)) * G + h) * G + w0) * 3) + (size_t)t * 4;
        f32x4 gv = __builtin_nontemporal_load((const f32x4*)(grids + off));
        float dv[4];
#pragma unroll
        for (int k = 0; k < 4; ++k) {
            int e = t * 4 + k;
            int i = e / 3;
            int c = e - 3 * i;
            float d = lds[c][j][i];
            dv[k] = d;                              // exact pass-through
            lds[c][j][i] = tanhf(gv[k] + d);        // same slot, same thread
        }
        __builtin_nontemporal_store(*(f32x4*)dv, (f32x4*)(defp + off));
    }
    __syncthreads();

    // ---- stage 3: trilinear sample + correction, out2 d-contig across threads
    const float SC = 0.5f * (TT - 1);
    for (int p = tid; p < 1024; p += 256) {
        int i = p >> 5;        // w offset
        int j = p & 31;        // d offset
        float ix = (lds[0][j][i] + 1.0f) * SC;
        float iy = (lds[1][j][i] + 1.0f) * SC;
        float iz = (lds[2][j][i] + 1.0f) * SC;
        float x0f = floorf(ix), y0f = floorf(iy), z0f = floorf(iz);
        float wx = ix - x0f, wy = iy - y0f, wz = iz - z0f;
        int x0 = min(max((int)x0f, 0), TT - 1);
        int y0 = min(max((int)y0f, 0), TT - 1);
        int z0 = min(max((int)z0f, 0), TT - 1);
        int x1 = min(x0 + 1, TT - 1);
        int y1 = min(y0 + 1, TT - 1);
        int z1 = min(z0 + 1, TT - 1);
        float mx = 1.0f - wx, my = 1.0f - wy, mz = 1.0f - wz;
        float w000 = mx * my * mz, w001 = wx * my * mz;
        float w010 = mx * wy * mz, w011 = wx * wy * mz;
        float w100 = mx * my * wz, w101 = wx * my * wz;
        float w110 = mx * wy * wz, w111 = wx * wy * wz;

        float r0, r1, r2, r3;
        if (PACKED) {
            const f32x4* tb = tmpl_cl + (size_t)b * CS;
            f32x4 v000 = tb[((size_t)z0 * TT + y0) * TT + x0];
            f32x4 v001 = tb[((size_t)z0 * TT + y0) * TT + x1];
            f32x4 v010 = tb[((size_t)z0 * TT + y1) * TT + x0];
            f32x4 v011 = tb[((size_t)z0 * TT + y1) * TT + x1];
            f32x4 v100 = tb[((size_t)z1 * TT + y0) * TT + x0];
            f32x4 v101 = tb[((size_t)z1 * TT + y0) * TT + x1];
            f32x4 v110 = tb[((size_t)z1 * TT + y1) * TT + x0];
            f32x4 v111 = tb[((size_t)z1 * TT + y1) * TT + x1];
            r0 = v000.x*w000 + v001.x*w001 + v010.x*w010 + v011.x*w011
               + v100.x*w100 + v101.x*w101 + v110.x*w110 + v111.x*w111;
            r1 = v000.y*w000 + v001.y*w001 + v010.y*w010 + v011.y*w011
               + v100.y*w100 + v101.y*w101 + v110.y*w110 + v111.y*w111;
            r2 = v000.z*w000 + v001.z*w001 + v010.z*w010 + v011.z*w011
               + v100.z*w100 + v101.z*w101 + v110.z*w110 + v111.z*w111;
            r3 = v000.w*w000 + v001.w*w001 + v010.w*w010 + v011.w*w011
               + v100.w*w100 + v101.w*w101 + v110.w*w110 + v111.w*w111;
        } else {
            size_t i000 = ((size_t)z0 * TT + y0) * TT + x0;
            size_t i001 = ((size_t)z0 * TT + y0) * TT + x1;
            size_t i010 = ((size_t)z0 * TT + y1) * TT + x0;
            size_t i011 = ((size_t)z0 * TT + y1) * TT + x1;
            size_t i100 = ((size_t)z1 * TT + y0) * TT + x0;
            size_t i101 = ((size_t)z1 * TT + y0) * TT + x1;
            size_t i110 = ((size_t)z1 * TT + y1) * TT + x0;
            size_t i111 = ((size_t)z1 * TT + y1) * TT + x1;
            float rr[4];
#pragma unroll
            for (int c = 0; c < NC; ++c) {
                const float* tb = tmpl_raw + ((size_t)b * NC + c) * CS;
                rr[c] = tb[i000]*w000 + tb[i001]*w001 + tb[i010]*w010 + tb[i011]*w011
                      + tb[i100]*w100 + tb[i101]*w101 + tb[i110]*w110 + tb[i111]*w111;
            }
            r0 = rr[0]; r1 = rr[1]; r2 = rr[2]; r3 = rr[3];
        }

        int w = w0 + i, d = d0 + j;
        size_t obase = ((((size_t)b * NC) * (size_t)G + w) * G + h) * G + d;
        const size_t cstride = (size_t)G * G * G;
        float c0 = __builtin_nontemporal_load(corr + obase + 0 * cstride);
        float c1 = __builtin_nontemporal_load(corr + obase + 1 * cstride);
        float c2 = __builtin_nontemporal_load(corr + obase + 2 * cstride);
        float c3 = __builtin_nontemporal_load(corr + obase + 3 * cstride);
        __builtin_nontemporal_store(r0 + c0, out2 + obase + 0 * cstride);
        __builtin_nontemporal_store(r1 + c1, out2 + obase + 1 * cstride);
        __builtin_nontemporal_store(r2 + c2, out2 + obase + 2 * cstride);
        __builtin_nontemporal_store(r3 + c3, out2 + obase + 3 * cstride);
    }
}

extern "C" void kernel_launch(void* const* d_in, const int* in_sizes, int n_in,
                              void* d_out, int out_size, void* d_ws, size_t ws_size,
                              hipStream_t stream) {
    const float* grids  = (const float*)d_in[0];
    const float* deform = (const float*)d_in[1];
    const float* corr   = (const float*)d_in[2];
    const float* tmpl   = (const float*)d_in[3];
    float* out2 = (float*)d_out;
    float* defp = out2 + (size_t)NB * NC * G * G * G;   // outputs concatenated flat
    f32x4* tmpl_cl = (f32x4*)d_ws;

    const size_t ws_needed = (size_t)NB * CS * sizeof(f32x4);  // 28.3 MB
    const bool packed = (ws_size >= ws_needed);

    if (packed) {
        int nv = NB * CS;
        tmpl_repack_kernel<<<(nv + 255) / 256, 256, 0, stream>>>(tmpl, tmpl_cl);
    }

    int nblk = NB * G * 16;   // (b,h) * 4 w-tiles * 4 d-tiles = 4096 blocks
    if (packed) {
        fused_sample_kernel<true><<<nblk, 256, 0, stream>>>(
            grids, deform, corr, tmpl_cl, tmpl, out2, defp);
    } else {
        fused_sample_kernel<false><<<nblk, 256, 0, stream>>>(
            grids, deform, corr, tmpl_cl, tmpl, out2, defp);
    }
}

// Round 2
// 347.170 us; speedup vs baseline: 1.1740x; 1.1637x over previous
//
#include <hip/hip_runtime.h>
#include <stdint.h>

#define G  128
#define TT 96
#define NB 2
#define NC 4
#define CS (TT * TT * TT)

typedef float f32x4 __attribute__((ext_vector_type(4)));
typedef float f32x2 __attribute__((ext_vector_type(2)));
typedef _Float16 f16x8 __attribute__((ext_vector_type(8)));
// 8-byte-aligned view for pair loads at odd-voxel offsets (HW needs dword align only)
typedef _Float16 f16x8u __attribute__((ext_vector_type(8), aligned(8)));

// Prepass: template [B,C,z,y,x] fp32 -> channels-last fp16 half4 [B,z,y,x] (8B/voxel).
// Each thread converts a pair of consecutive voxels -> one 16B store.
__global__ __launch_bounds__(256) void tmpl_repack_f16(
        const float* __restrict__ tmpl, f16x8* __restrict__ out) {
    const int NP = NB * (CS / 2);   // voxel pairs
    int idx = blockIdx.x * 256 + threadIdx.x;
    if (idx >= NP) return;
    int b  = idx / (CS / 2);
    int s2 = idx - b * (CS / 2);
    const float* base = tmpl + (size_t)b * NC * CS + (size_t)s2 * 2;
    f16x8 o;
#pragma unroll
    for (int c = 0; c < NC; ++c) {
        f32x2 v = *(const f32x2*)(base + (size_t)c * CS);   // 8B coalesced
        o[c]     = (_Float16)v.x;
        o[4 + c] = (_Float16)v.y;
    }
    out[idx] = o;   // 16B coalesced; packed template is the gather working set
}

// One block = tile of 32(d) x 32(w) at fixed (b, h).
// Single LDS buffer [c][j=d][i=w]; stage2 overwrites def with tanh(field) in-place.
template <bool PACKED>
__global__ __launch_bounds__(256, 8) void fused_sample_kernel(
        const float* __restrict__ grids,
        const float* __restrict__ deform,
        const float* __restrict__ corr,
        const f16x8* __restrict__ tmpl_f16,   // used when PACKED
        const float* __restrict__ tmpl_raw,   // used when !PACKED
        float* __restrict__ out2,
        float* __restrict__ defp) {
    __shared__ float lds[3][32][33];    // [c][j=d][i=w] (+1 pad)

    int blk = blockIdx.x;
    int wt = blk & 3;
    int dt = (blk >> 2) & 3;
    int h  = (blk >> 4) & 127;
    int b  = blk >> 11;
    int w0 = wt << 5, d0 = dt << 5;
    int tid = threadIdx.x;

    // ---- stage 1: deformation -> lds[c][j][i], 16B vector loads along d,
    //      transposed scatter into LDS
    for (int idx = tid; idx < 768; idx += 256) {   // 3c * 32i * 8 quads
        int c   = idx >> 8;
        int rem = idx & 255;
        int i   = rem >> 3;
        int j4  = (rem & 7) << 2;
        size_t off = ((((size_t)b * 3 + c) * G + (w0 + i)) * G + h) * G + (d0 + j4);
        f32x4 v = __builtin_nontemporal_load((const f32x4*)(deform + off));
        lds[c][j4 + 0][i] = v.x;
        lds[c][j4 + 1][i] = v.y;
        lds[c][j4 + 2][i] = v.z;
        lds[c][j4 + 3][i] = v.w;
    }
    __syncthreads();

    // ---- stage 2: grids row (96 floats contiguous in (w,c)) -> field in-place;
    //      defp write (exact pass-through of deform)
    for (int idx = tid; idx < 768; idx += 256) {   // 32 rows * 24 float4-chunks
        int j = idx / 24;
        int t = idx - j * 24;
        size_t off = (((((size_t)b * G + (d0 + j)) * G + h) * G + w0) * 3) + (size_t)t * 4;
        f32x4 gv = __builtin_nontemporal_load((const f32x4*)(grids + off));
        float dv[4];
#pragma unroll
        for (int k = 0; k < 4; ++k) {
            int e = t * 4 + k;
            int i = e / 3;
            int c = e - 3 * i;
            float d = lds[c][j][i];
            dv[k] = d;                              // exact pass-through
            lds[c][j][i] = tanhf(gv[k] + d);        // same slot, same thread
        }
        __builtin_nontemporal_store(*(f32x4*)dv, (f32x4*)(defp + off));
    }
    __syncthreads();

    // ---- stage 3: trilinear sample + correction, out2 d-contig across threads
    const float SC = 0.5f * (TT - 1);
    const char* tb16 = (const char*)tmpl_f16 + (size_t)b * ((size_t)CS * 8);
    for (int p = tid; p < 1024; p += 256) {
        int i = p >> 5;        // w offset
        int j = p & 31;        // d offset
        float ix = (lds[0][j][i] + 1.0f) * SC;
        float iy = (lds[1][j][i] + 1.0f) * SC;
        float iz = (lds[2][j][i] + 1.0f) * SC;
        // tanh in [-1,1] => ix,iy,iz in [0,95]. Clamp base to [0,94] and
        // recompute the fraction: exactly equivalent to ref's clip semantics
        // (at ix==95, wx==1 selects t[95] exactly).
        int x0 = min(max((int)floorf(ix), 0), TT - 2);
        int y0 = min(max((int)floorf(iy), 0), TT - 2);
        int z0 = min(max((int)floorf(iz), 0), TT - 2);
        float wx = ix - (float)x0;
        float wy = iy - (float)y0;
        float wz = iz - (float)z0;
        float mx = 1.0f - wx, my = 1.0f - wy, mz = 1.0f - wz;

        float r0, r1, r2, r3;
        if (PACKED) {
            int y1 = y0 + 1, z1 = z0 + 1;
            int zy00 = (z0 * TT + y0) * TT + x0;
            int zy01 = (z0 * TT + y1) * TT + x0;
            int zy10 = (z1 * TT + y0) * TT + x0;
            int zy11 = (z1 * TT + y1) * TT + x0;
            // one 16B load per (z,y) row: both x-corners, all 4 channels
            f16x8 v00 = *(const f16x8u*)(tb16 + (size_t)zy00 * 8);
            f16x8 v01 = *(const f16x8u*)(tb16 + (size_t)zy01 * 8);
            f16x8 v10 = *(const f16x8u*)(tb16 + (size_t)zy10 * 8);
            f16x8 v11 = *(const f16x8u*)(tb16 + (size_t)zy11 * 8);
            float a00 = my * mz, a01 = wy * mz, a10 = my * wz, a11 = wy * wz;
            float r[4];
#pragma unroll
            for (int c = 0; c < NC; ++c) {
                float t00 = (float)v00[c] * mx + (float)v00[4 + c] * wx;
                float t01 = (float)v01[c] * mx + (float)v01[4 + c] * wx;
                float t10 = (float)v10[c] * mx + (float)v10[4 + c] * wx;
                float t11 = (float)v11[c] * mx + (float)v11[4 + c] * wx;
                r[c] = t00 * a00 + t01 * a01 + t10 * a10 + t11 * a11;
            }
            r0 = r[0]; r1 = r[1]; r2 = r[2]; r3 = r[3];
        } else {
            int x1 = x0 + 1, y1 = y0 + 1, z1 = z0 + 1;
            float w000 = mx * my * mz, w001 = wx * my * mz;
            float w010 = mx * wy * mz, w011 = wx * wy * mz;
            float w100 = mx * my * wz, w101 = wx * my * wz;
            float w110 = mx * wy * wz, w111 = wx * wy * wz;
            size_t i000 = ((size_t)z0 * TT + y0) * TT + x0;
            size_t i001 = ((size_t)z0 * TT + y0) * TT + x1;
            size_t i010 = ((size_t)z0 * TT + y1) * TT + x0;
            size_t i011 = ((size_t)z0 * TT + y1) * TT + x1;
            size_t i100 = ((size_t)z1 * TT + y0) * TT + x0;
            size_t i101 = ((size_t)z1 * TT + y0) * TT + x1;
            size_t i110 = ((size_t)z1 * TT + y1) * TT + x0;
            size_t i111 = ((size_t)z1 * TT + y1) * TT + x1;
            float rr[4];
#pragma unroll
            for (int c = 0; c < NC; ++c) {
                const float* tb = tmpl_raw + ((size_t)b * NC + c) * CS;
                rr[c] = tb[i000]*w000 + tb[i001]*w001 + tb[i010]*w010 + tb[i011]*w011
                      + tb[i100]*w100 + tb[i101]*w101 + tb[i110]*w110 + tb[i111]*w111;
            }
            r0 = rr[0]; r1 = rr[1]; r2 = rr[2]; r3 = rr[3];
        }

        int w = w0 + i, d = d0 + j;
        size_t obase = ((((size_t)b * NC) * (size_t)G + w) * G + h) * G + d;
        const size_t cstride = (size_t)G * G * G;
        float c0 = __builtin_nontemporal_load(corr + obase + 0 * cstride);
        float c1 = __builtin_nontemporal_load(corr + obase + 1 * cstride);
        float c2 = __builtin_nontemporal_load(corr + obase + 2 * cstride);
        float c3 = __builtin_nontemporal_load(corr + obase + 3 * cstride);
        __builtin_nontemporal_store(r0 + c0, out2 + obase + 0 * cstride);
        __builtin_nontemporal_store(r1 + c1, out2 + obase + 1 * cstride);
        __builtin_nontemporal_store(r2 + c2, out2 + obase + 2 * cstride);
        __builtin_nontemporal_store(r3 + c3, out2 + obase + 3 * cstride);
    }
}

extern "C" void kernel_launch(void* const* d_in, const int* in_sizes, int n_in,
                              void* d_out, int out_size, void* d_ws, size_t ws_size,
                              hipStream_t stream) {
    const float* grids  = (const float*)d_in[0];
    const float* deform = (const float*)d_in[1];
    const float* corr   = (const float*)d_in[2];
    const float* tmpl   = (const float*)d_in[3];
    float* out2 = (float*)d_out;
    float* defp = out2 + (size_t)NB * NC * G * G * G;   // outputs concatenated flat
    f16x8* tmpl_f16 = (f16x8*)d_ws;

    const size_t ws_needed = (size_t)NB * CS * 8;   // 14.2 MB fp16 packed
    const bool packed = (ws_size >= ws_needed);

    if (packed) {
        int np = NB * (CS / 2);
        tmpl_repack_f16<<<(np + 255) / 256, 256, 0, stream>>>(tmpl, tmpl_f16);
    }

    int nblk = NB * G * 16;   // (b,h) * 4 w-tiles * 4 d-tiles = 4096 blocks
    if (packed) {
        fused_sample_kernel<true><<<nblk, 256, 0, stream>>>(
            grids, deform, corr, tmpl_f16, tmpl, out2, defp);
    } else {
        fused_sample_kernel<false><<<nblk, 256, 0, stream>>>(
            grids, deform, corr, tmpl_f16, tmpl, out2, defp);
    }
}

// Round 4
// 333.300 us; speedup vs baseline: 1.2229x; 1.0416x over previous
//
#include <hip/hip_runtime.h>
#include <stdint.h>

#define G  128
#define TT 96
#define NB 2
#define NC 4
#define CS (TT * TT * TT)

typedef float f32x4 __attribute__((ext_vector_type(4)));
typedef float f32x2 __attribute__((ext_vector_type(2)));
typedef _Float16 f16x8 __attribute__((ext_vector_type(8)));
// 8-byte-aligned view for pair loads at odd-voxel offsets (HW needs dword align only)
typedef _Float16 f16x8u __attribute__((ext_vector_type(8), aligned(8)));

// Prepass: template [B,C,z,y,x] fp32 -> channels-last fp16 half4 [B,z,y,x] (8B/voxel).
__global__ __launch_bounds__(256) void tmpl_repack_f16(
        const float* __restrict__ tmpl, f16x8* __restrict__ out) {
    const int NP = NB * (CS / 2);   // voxel pairs
    int idx = blockIdx.x * 256 + threadIdx.x;
    if (idx >= NP) return;
    int b  = idx / (CS / 2);
    int s2 = idx - b * (CS / 2);
    const float* base = tmpl + (size_t)b * NC * CS + (size_t)s2 * 2;
    f16x8 o;
#pragma unroll
    for (int c = 0; c < NC; ++c) {
        f32x2 v = *(const f32x2*)(base + (size_t)c * CS);   // 8B coalesced
        o[c]     = (_Float16)v.x;
        o[4 + c] = (_Float16)v.y;
    }
    out[idx] = o;   // 16B coalesced; packed template is the gather working set
}

// One block = tile of 32(d) x 32(w) at fixed (b, h).
// LDS [c][i=w][j=d], row stride 36 (16B-aligned quads, 4-bank skew per row).
// Stage 2 overwrites deform with tanh(field) in place (same slot, same thread).
// Stage 3: each thread owns 4 d-consecutive points -> issues all 16 template
// gathers before consuming (MLP 4 -> 16) and does float4 corr/out2 traffic.
template <bool PACKED>
__global__ __launch_bounds__(256, 4) void fused_sample_kernel(
        const float* __restrict__ grids,
        const float* __restrict__ deform,
        const float* __restrict__ corr,
        const f16x8* __restrict__ tmpl_f16,   // used when PACKED
        const float* __restrict__ tmpl_raw,   // used when !PACKED
        float* __restrict__ out2,
        float* __restrict__ defp) {
    __shared__ float lds[3][32][36];    // [c][i=w][j=d]

    int blk = blockIdx.x;
    int wt = blk & 3;
    int dt = (blk >> 2) & 3;
    int h  = (blk >> 4) & 127;
    int b  = blk >> 11;
    int w0 = wt << 5, d0 = dt << 5;
    int tid = threadIdx.x;

    // ---- stage 1: deformation -> lds[c][i][j4..j4+3], 16B global + 16B LDS writes
    for (int idx = tid; idx < 768; idx += 256) {   // 3c * 32i * 8 quads
        int c   = idx >> 8;
        int rem = idx & 255;
        int i   = rem >> 3;
        int j4  = (rem & 7) << 2;
        size_t off = ((((size_t)b * 3 + c) * G + (w0 + i)) * G + h) * G + (d0 + j4);
        f32x4 v = __builtin_nontemporal_load((const f32x4*)(deform + off));
        *(f32x4*)&lds[c][i][j4] = v;   // ((c*32+i)*36 + j4)*4 is 16B-aligned
    }
    __syncthreads();

    // ---- stage 2: grids row (96 floats contiguous in (w,c)) -> field in-place;
    //      defp write (exact pass-through of deform)
    for (int idx = tid; idx < 768; idx += 256) {   // 32 rows * 24 float4-chunks
        int j = idx / 24;
        int t = idx - j * 24;
        size_t off = (((((size_t)b * G + (d0 + j)) * G + h) * G + w0) * 3) + (size_t)t * 4;
        f32x4 gv = __builtin_nontemporal_load((const f32x4*)(grids + off));
        float dv[4];
#pragma unroll
        for (int k = 0; k < 4; ++k) {
            int e = t * 4 + k;
            int i = e / 3;
            int c = e - 3 * i;
            float d = lds[c][i][j];
            dv[k] = d;                              // exact pass-through
            lds[c][i][j] = tanhf(gv[k] + d);        // same slot, same thread
        }
        __builtin_nontemporal_store(*(f32x4*)dv, (f32x4*)(defp + off));
    }
    __syncthreads();

    // ---- stage 3: 4 d-consecutive points per thread
    const float SC = 0.5f * (TT - 1);
    const char* tb16 = (const char*)tmpl_f16 + (size_t)b * ((size_t)CS * 8);
    {
        int i  = tid >> 3;          // w offset
        int j4 = (tid & 7) << 2;    // d offset (4 consecutive)

        f32x4 fx = *(const f32x4*)&lds[0][i][j4];
        f32x4 fy = *(const f32x4*)&lds[1][i][j4];
        f32x4 fz = *(const f32x4*)&lds[2][i][j4];

        float wx[4], wy[4], wz[4];
        int base[4];
#pragma unroll
        for (int k = 0; k < 4; ++k) {
            float ix = (fx[k] + 1.0f) * SC;
            float iy = (fy[k] + 1.0f) * SC;
            float iz = (fz[k] + 1.0f) * SC;
            // tanh in [-1,1] => coords in [0,95]; clamp base to [0,94] and
            // recompute fraction: exactly matches ref clip semantics.
            int x0 = min(max((int)floorf(ix), 0), TT - 2);
            int y0 = min(max((int)floorf(iy), 0), TT - 2);
            int z0 = min(max((int)floorf(iz), 0), TT - 2);
            wx[k] = ix - (float)x0;
            wy[k] = iy - (float)y0;
            wz[k] = iz - (float)z0;
            base[k] = (z0 * TT + y0) * TT + x0;
        }

        float r[4][4];   // [k][c]
        if (PACKED) {
            // issue ALL 16 gather loads before any consumption
            f16x8 v00[4], v01[4], v10[4], v11[4];
#pragma unroll
            for (int k = 0; k < 4; ++k) {
                v00[k] = *(const f16x8u*)(tb16 + ((size_t)base[k]) * 8);
                v01[k] = *(const f16x8u*)(tb16 + ((size_t)(base[k] + TT)) * 8);
                v10[k] = *(const f16x8u*)(tb16 + ((size_t)(base[k] + TT * TT)) * 8);
                v11[k] = *(const f16x8u*)(tb16 + ((size_t)(base[k] + TT * TT + TT)) * 8);
            }
#pragma unroll
            for (int k = 0; k < 4; ++k) {
                float mx = 1.0f - wx[k], my = 1.0f - wy[k], mz = 1.0f - wz[k];
                float a00 = my * mz, a01 = wy[k] * mz;
                float a10 = my * wz[k], a11 = wy[k] * wz[k];
#pragma unroll
                for (int c = 0; c < NC; ++c) {
                    float t00 = (float)v00[k][c] * mx + (float)v00[k][4 + c] * wx[k];
                    float t01 = (float)v01[k][c] * mx + (float)v01[k][4 + c] * wx[k];
                    float t10 = (float)v10[k][c] * mx + (float)v10[k][4 + c] * wx[k];
                    float t11 = (float)v11[k][c] * mx + (float)v11[k][4 + c] * wx[k];
                    r[k][c] = t00 * a00 + t01 * a01 + t10 * a10 + t11 * a11;
                }
            }
        } else {
#pragma unroll
            for (int k = 0; k < 4; ++k) {
                float mx = 1.0f - wx[k], my = 1.0f - wy[k], mz = 1.0f - wz[k];
                float w000 = mx * my * mz, w001 = wx[k] * my * mz;
                float w010 = mx * wy[k] * mz, w011 = wx[k] * wy[k] * mz;
                float w100 = mx * my * wz[k], w101 = wx[k] * my * wz[k];
                float w110 = mx * wy[k] * wz[k], w111 = wx[k] * wy[k] * wz[k];
                size_t i000 = (size_t)base[k];
                size_t i001 = i000 + 1;
                size_t i010 = i000 + TT;
                size_t i011 = i010 + 1;
                size_t i100 = i000 + TT * TT;
                size_t i101 = i100 + 1;
                size_t i110 = i100 + TT;
                size_t i111 = i110 + 1;
#pragma unroll
                for (int c = 0; c < NC; ++c) {
                    const float* tb = tmpl_raw + ((size_t)b * NC + c) * CS;
                    r[k][c] = tb[i000]*w000 + tb[i001]*w001 + tb[i010]*w010 + tb[i011]*w011
                            + tb[i100]*w100 + tb[i101]*w101 + tb[i110]*w110 + tb[i111]*w111;
                }
            }
        }

        int w = w0 + i, d = d0 + j4;
        size_t obase = ((((size_t)b * NC) * (size_t)G + w) * G + h) * G + d;
        const size_t cstride = (size_t)G * G * G;
#pragma unroll
        for (int c = 0; c < NC; ++c) {
            f32x4 cv = __builtin_nontemporal_load((const f32x4*)(corr + obase + c * cstride));
            f32x4 ov;
            ov.x = r[0][c] + cv.x;
            ov.y = r[1][c] + cv.y;
            ov.z = r[2][c] + cv.z;
            ov.w = r[3][c] + cv.w;
            __builtin_nontemporal_store(ov, (f32x4*)(out2 + obase + c * cstride));
        }
    }
}

extern "C" void kernel_launch(void* const* d_in, const int* in_sizes, int n_in,
                              void* d_out, int out_size, void* d_ws, size_t ws_size,
                              hipStream_t stream) {
    const float* grids  = (const float*)d_in[0];
    const float* deform = (const float*)d_in[1];
    const float* corr   = (const float*)d_in[2];
    const float* tmpl   = (const float*)d_in[3];
    float* out2 = (float*)d_out;
    float* defp = out2 + (size_t)NB * NC * G * G * G;   // outputs concatenated flat
    f16x8* tmpl_f16 = (f16x8*)d_ws;

    const size_t ws_needed = (size_t)NB * CS * 8;   // 14.2 MB fp16 packed
    const bool packed = (ws_size >= ws_needed);

    if (packed) {
        int np = NB * (CS / 2);
        tmpl_repack_f16<<<(np + 255) / 256, 256, 0, stream>>>(tmpl, tmpl_f16);
    }

    int nblk = NB * G * 16;   // (b,h) * 4 w-tiles * 4 d-tiles = 4096 blocks
    if (packed) {
        fused_sample_kernel<true><<<nblk, 256, 0, stream>>>(
            grids, deform, corr, tmpl_f16, tmpl, out2, defp);
    } else {
        fused_sample_kernel<false><<<nblk, 256, 0, stream>>>(
            grids, deform, corr, tmpl_f16, tmpl, out2, defp);
    }
}